// Round 4
// baseline (154.630 us; speedup 1.0000x reference)
//
#include <hip/hip_runtime.h>
#include <hip/hip_bf16.h>
#include <stdint.h>
#include <stddef.h>

#define L_LEN 4096
#define CIN   128
#define COUT  128
#define NB    32
#define KTOT  384            // 3 * CIN, kappa = k*128 + i; t = kappa/32
#define TN    32             // h-tile per block
#define ROWS  (TN + 2)       // 34 (halo of 1 each side)

typedef __bf16 bf16x8 __attribute__((ext_vector_type(8)));
typedef float  f32x4  __attribute__((ext_vector_type(4)));

__device__ __forceinline__ uint16_t f2bf(float f) {
    union { float f; uint32_t u; } v; v.f = f;
    return (uint16_t)((v.u + 0x7fffu + ((v.u >> 16) & 1u)) >> 16);  // RNE
}
__device__ __forceinline__ uint32_t pack2(float lo, float hi) {
    return (uint32_t)f2bf(lo) | ((uint32_t)f2bf(hi) << 16);
}

// ---- Prologue: Wc2 in MFMA A-fragment order + cbias ----
// Wc2 flat index e = (((b*12 + t)*8 + og)*64 + lane)*8 + j
//   o = og*16 + (lane&15); kappa = t*32 + (lane>>4)*8 + j; k=kappa>>7; i=kappa&127
__global__ __launch_bounds__(256) void geps_combine(
    const float* __restrict__ codes, const float* __restrict__ weight,
    const float* __restrict__ Amat,  const float* __restrict__ Bmat,
    const float* __restrict__ bias,  const float* __restrict__ bias_ctx,
    uint16_t* __restrict__ Wc2, float* __restrict__ cbias)
{
    int tid = blockIdx.x * 256 + threadIdx.x;
    if (tid < NB * COUT * KTOT) {
        int j    = tid & 7;
        int lane = (tid >> 3) & 63;
        int og   = (tid >> 9) & 7;
        int x    = tid >> 12;            // b*12 + t, in [0, 384)
        int b    = x / 12;
        int t    = x - b * 12;
        int o    = og * 16 + (lane & 15);
        int kap  = t * 32 + (lane >> 4) * 8 + j;
        int k    = kap >> 7;
        int i    = kap & 127;
        float cw = 0.f;
        #pragma unroll
        for (int c = 0; c < 2; ++c) {
            float a = Amat[i * 6 + c * 3 + k];
            #pragma unroll
            for (int r = 0; r < 2; ++r)
                cw += a * codes[b * 4 + c * 2 + r] * Bmat[o * 6 + r * 3 + k];
        }
        Wc2[tid] = f2bf(weight[o * 384 + i * 3 + k] + cw);   // FACTOR = 1
    }
    if (tid < NB * COUT) {
        int b = tid >> 7, o = tid & 127;
        float cb = bias[o];
        #pragma unroll
        for (int c = 0; c < 2; ++c)
            cb += codes[b * 4 + c * 2 + c] * bias_ctx[c * 128 + o];
        cbias[tid] = cb;
    }
}

// ---- Main: 4096 small blocks (32h x 128o), 8 blocks/CU, 64-VGPR cap ----
__global__ __launch_bounds__(256, 8) void geps_conv(
    const float* __restrict__ in, const uint16_t* __restrict__ Wc2,
    const float* __restrict__ cbias, float* __restrict__ out)
{
    // Xt: element (r,i) at r*128 + ((i>>3 ^ (r&15))<<3) + (i&7)
    __shared__ uint16_t __attribute__((aligned(16))) Xt[ROWS * 128];
    __shared__ float cb[COUT];

    const int tid  = threadIdx.x;
    const int b    = blockIdx.y;
    const int h0   = blockIdx.x * TN;
    const int lane = tid & 63;
    const int wid  = tid >> 6;
    const int m16  = lane & 15;
    const int q    = lane >> 4;
    const int mq   = wid * 32;           // wave's o-offset

    if (tid < COUT) cb[tid] = cbias[b * COUT + tid];

    const float* inb = in + (size_t)b * CIN * L_LEN;

    // --- core transpose: 64 i-pairs x 8 h-quads = 512 tasks, 2/thread ---
    #pragma unroll
    for (int it = 0; it < 2; ++it) {
        int task = it * 256 + tid;
        int p    = task >> 3;            // i-pair (i = 2p, 2p+1)
        int qd   = task & 7;             // h-quad
        const float* r0 = inb + (size_t)(2 * p) * L_LEN + h0 + 4 * qd;
        const float4 a  = *(const float4*)r0;
        const float4 c  = *(const float4*)(r0 + L_LEN);
        const int off   = (2 * p) & 7;
        const int pc    = p >> 2;
        const float av[4] = {a.x, a.y, a.z, a.w};
        const float cv[4] = {c.x, c.y, c.z, c.w};
        #pragma unroll
        for (int j = 0; j < 4; ++j) {
            int r  = 1 + 4 * qd + j;
            int ch = pc ^ (r & 15);
            *(uint32_t*)&Xt[r * 128 + (ch << 3) + off] = pack2(av[j], cv[j]);
        }
    }
    // --- halo columns r=0 (h0-1) and r=33 (h0+32), circular ---
    if (tid < 128) {
        int p    = tid & 63;
        int side = tid >> 6;
        int r    = side ? (ROWS - 1) : 0;
        int gh   = (h0 - 1 + r) & (L_LEN - 1);
        float x0 = inb[(size_t)(2 * p)     * L_LEN + gh];
        float x1 = inb[(size_t)(2 * p + 1) * L_LEN + gh];
        int ch   = (p >> 2) ^ (r & 15);
        *(uint32_t*)&Xt[r * 128 + (ch << 3) + ((2 * p) & 7)] = pack2(x0, x1);
    }

    f32x4 acc[2][2];
    #pragma unroll
    for (int a = 0; a < 2; ++a)
        #pragma unroll
        for (int c = 0; c < 2; ++c) acc[a][c] = 0.0f;

    // fragment-major A base for this wave: og0 = wid*2
    const uint16_t* afb = Wc2 + ((((size_t)b * 12) * 8 + wid * 2) << 9) + lane * 8;

    __syncthreads();                     // only barrier

    #pragma unroll 2
    for (int t = 0; t < 12; ++t) {
        const int k   = t >> 2;
        const int i0c = (t & 3) * 4;
        bf16x8 af[2], bf[2];
        #pragma unroll
        for (int mt = 0; mt < 2; ++mt)
            af[mt] = *(const bf16x8*)(afb + ((t * 8 + mt) << 9));
        #pragma unroll
        for (int nt = 0; nt < 2; ++nt) {
            int r  = nt * 16 + m16 + k;
            int ch = (i0c + q) ^ (r & 15);
            bf[nt] = *(const bf16x8*)&Xt[r * 128 + (ch << 3)];
        }
        #pragma unroll
        for (int mt = 0; mt < 2; ++mt)
            #pragma unroll
            for (int nt = 0; nt < 2; ++nt)
                acc[mt][nt] = __builtin_amdgcn_mfma_f32_16x16x32_bf16(
                    af[mt], bf[nt], acc[mt][nt], 0, 0, 0);
    }

    // --- epilogue: C/D col=lane&15 (h), row=(lane>>4)*4+reg (o) ---
    float* outb = out + (size_t)b * COUT * L_LEN + h0;
    #pragma unroll
    for (int mt = 0; mt < 2; ++mt) {
        #pragma unroll
        for (int reg = 0; reg < 4; ++reg) {
            int o = mq + mt * 16 + q * 4 + reg;
            float bv = cb[o];
            float* orow = outb + (size_t)o * L_LEN;
            #pragma unroll
            for (int nt = 0; nt < 2; ++nt)
                orow[nt * 16 + m16] = acc[mt][nt][reg] + bv;
        }
    }
}

extern "C" void kernel_launch(void* const* d_in, const int* in_sizes, int n_in,
                              void* d_out, int out_size, void* d_ws, size_t ws_size,
                              hipStream_t stream) {
    const float* input    = (const float*)d_in[0];
    const float* codes    = (const float*)d_in[1];
    const float* weight   = (const float*)d_in[2];
    const float* Amat     = (const float*)d_in[3];
    const float* Bmat     = (const float*)d_in[4];
    const float* bias     = (const float*)d_in[5];
    const float* bias_ctx = (const float*)d_in[6];
    float* out = (float*)d_out;

    uint16_t* Wc2   = (uint16_t*)d_ws;
    float*    cbias = (float*)((char*)d_ws + (size_t)NB * COUT * KTOT * 2);

    geps_combine<<<dim3((NB * COUT * KTOT) / 256), 256, 0, stream>>>(
        codes, weight, Amat, Bmat, bias, bias_ctx, Wc2, cbias);
    geps_conv<<<dim3(L_LEN / TN, NB), 256, 0, stream>>>(input, Wc2, cbias, out);
}